// Round 16
// baseline (124.846 us; speedup 1.0000x reference)
//
#include <hip/hip_runtime.h>
#include <stdint.h>

typedef __attribute__((ext_vector_type(8))) __bf16 bf16x8;
typedef __attribute__((ext_vector_type(4))) float f32x4;
typedef __attribute__((ext_vector_type(4))) unsigned short u16x4;

typedef __attribute__((address_space(1))) unsigned int as1_uint;
typedef __attribute__((address_space(3))) unsigned int as3_uint;

__device__ __forceinline__ unsigned short f2bf(float f) {
  unsigned int u = __float_as_uint(f);
  u += 0x7fffu + ((u >> 16) & 1u);
  return (unsigned short)(u >> 16);
}

__device__ __forceinline__ void gload_lds16(const void* g, void* l) {
  __builtin_amdgcn_global_load_lds((as1_uint*)(uintptr_t)g, (as3_uint*)(uintptr_t)l,
                                   16, 0, 0);
}

// ---- fused fp32->bf16 converts: 4 elementwise inputs + o_proj transpose ----
// blocks [0,10240): elementwise (x, qp, kp, vp); [10240,11264): transpose op->opT
__global__ __launch_bounds__(256)
void cvt_fused(const float* __restrict__ x, const float* __restrict__ qp,
               const float* __restrict__ kp, const float* __restrict__ vp,
               const float* __restrict__ op,
               unsigned short* __restrict__ xb, unsigned short* __restrict__ qpb,
               unsigned short* __restrict__ kpb, unsigned short* __restrict__ vpb,
               unsigned short* __restrict__ opT) {
  __shared__ unsigned short t[64][72];
  const int b = blockIdx.x;
  if (b < 10240) {
    const float* in;
    unsigned short* out;
    int base;
    if (b < 4096)      { in = x;  out = xb;  base = b; }
    else if (b < 8192) { in = qp; out = qpb; base = b - 4096; }
    else if (b < 9216) { in = kp; out = kpb; base = b - 8192; }
    else               { in = vp; out = vpb; base = b - 9216; }
    const int i = base * 256 + threadIdx.x;
    float4 v = ((const float4*)in)[i];
    u16x4 o;
    o[0] = f2bf(v.x); o[1] = f2bf(v.y); o[2] = f2bf(v.z); o[3] = f2bf(v.w);
    ((u16x4*)out)[i] = o;
    return;
  }
  // transpose-convert: op [2048][2048] -> opT [2048][2048]
  const int tb = b - 10240;
  const int tj = (tb & 31) * 64;
  const int ti = (tb >> 5) * 64;
  const int r  = threadIdx.x >> 4;
  const int c4 = (threadIdx.x & 15) * 4;
#pragma unroll
  for (int i = 0; i < 4; ++i) {
    int row = r + i * 16;
    float4 v = *(const float4*)&op[(size_t)(ti + row) * 2048 + tj + c4];
    t[row][c4]     = f2bf(v.x);
    t[row][c4 + 1] = f2bf(v.y);
    t[row][c4 + 2] = f2bf(v.z);
    t[row][c4 + 3] = f2bf(v.w);
  }
  __syncthreads();
#pragma unroll
  for (int i = 0; i < 4; ++i) {
    int orow = r + i * 16;
    u16x4 o;
    o[0] = t[c4][orow]; o[1] = t[c4 + 1][orow];
    o[2] = t[c4 + 2][orow]; o[3] = t[c4 + 3][orow];
    *(u16x4*)&opT[(size_t)(tj + orow) * 2048 + ti + c4] = o;
  }
}

// ---------------- NT GEMM body: C[M][N] = A[M][K] * B[N][K]^T, bf16 MFMA --------
template <int BN, bool OUT_BF16>
__device__ __forceinline__
void gemm_body(const unsigned short* __restrict__ A,
               const unsigned short* __restrict__ B,
               void* __restrict__ Cout, int N, int K, float alpha,
               int bx, int by, unsigned short* lA, unsigned short* lB) {
  constexpr int NF  = BN / 32;   // 16-col fragments per wave
  constexpr int ASZ = 64 * 64;
  constexpr int BSZ = BN * 64;
  const int tid  = threadIdx.x;
  const int lane = tid & 63;
  const int w    = tid >> 6;
  const int wr   = (w >> 1) * 32;
  const int wc   = (w & 1) * (BN / 2);
  const long brow = (long)by * 64;
  const long bcol = (long)bx * BN;
  const int lr = lane & 15;
  const int lq = lane >> 4;

  const int row0 = tid >> 3;
  const int lc0  = (tid & 7) ^ (row0 & 7);

  f32x4 acc[2][NF] = {};

  const unsigned short* gA = A + (brow + row0) * (long)K + lc0 * 8;
  const unsigned short* gB = B + (bcol + row0) * (long)K + lc0 * 8;

#define G_STAGE(buf, k0)                                                          \
  {                                                                               \
    gload_lds16(gA + (k0),           lA + (buf) * ASZ + tid * 8);                 \
    gload_lds16(gA + 32l * K + (k0), lA + (buf) * ASZ + 2048 + tid * 8);          \
    _Pragma("unroll")                                                             \
    for (int g = 0; g < NF; ++g)                                                  \
      gload_lds16(gB + g * 32l * K + (k0), lB + (buf) * BSZ + g * 2048 + tid * 8);\
  }

  G_STAGE(0, 0);
  __syncthreads();

  for (int k0 = 0; k0 < K; k0 += 64) {
    const int cur = (k0 >> 6) & 1;
    if (k0 + 64 < K) G_STAGE(cur ^ 1, k0 + 64);  // prefetch rides through compute
#pragma unroll
    for (int kk = 0; kk < 2; ++kk) {
      const int j = kk * 4 + lq;
      const int ra0 = wr + lr, ra1 = wr + 16 + lr;
      bf16x8 a0 = *(const bf16x8*)&lA[cur * ASZ + ra0 * 64 + ((j ^ (ra0 & 7)) << 3)];
      bf16x8 a1 = *(const bf16x8*)&lA[cur * ASZ + ra1 * 64 + ((j ^ (ra1 & 7)) << 3)];
      bf16x8 b[NF];
#pragma unroll
      for (int n = 0; n < NF; ++n) {
        const int rb = wc + n * 16 + lr;
        b[n] = *(const bf16x8*)&lB[cur * BSZ + rb * 64 + ((j ^ (rb & 7)) << 3)];
      }
#pragma unroll
      for (int n = 0; n < NF; ++n) {
        acc[0][n] = __builtin_amdgcn_mfma_f32_16x16x32_bf16(a0, b[n], acc[0][n], 0, 0, 0);
        acc[1][n] = __builtin_amdgcn_mfma_f32_16x16x32_bf16(a1, b[n], acc[1][n], 0, 0, 0);
      }
    }
    __syncthreads();
  }
#undef G_STAGE

  const int orow = (int)brow + wr + lq * 4;
  const int ocol = (int)bcol + wc + lr;
#pragma unroll
  for (int m = 0; m < 2; ++m)
#pragma unroll
    for (int n = 0; n < NF; ++n)
#pragma unroll
      for (int r = 0; r < 4; ++r) {
        size_t row = (size_t)(orow + m * 16 + r);
        size_t col = (size_t)(ocol + n * 16);
        float v = acc[m][n][r] * alpha;
        if (OUT_BF16)
          ((unsigned short*)Cout)[row * N + col] = f2bf(v);
        else
          ((float*)Cout)[row * N + col] = v;
      }
}

template <int BN, bool OUT_BF16>
__global__ __launch_bounds__(256)
void gemm_nt(const unsigned short* __restrict__ A,
             const unsigned short* __restrict__ B,
             void* __restrict__ Cout, int N, int K, float alpha) {
  __shared__ unsigned short lA[2 * 64 * 64];
  __shared__ unsigned short lB[2 * BN * 64];
  gemm_body<BN, OUT_BF16>(A, B, Cout, N, K, alpha, blockIdx.x, blockIdx.y, lA, lB);
}

// Fused Q+K+V projections, one dispatch, flat 768-block decode (all BN=128):
//   [0,512)   Q = xb @ qpb^T (alpha=log2e/8), 16x * 32y
//   [512,640) K = xb @ kpb^T,                  4x * 32y
//   [640,768) Vt = vpb @ xb^T,                16x *  8y
__global__ __launch_bounds__(256)
void gemm_proj(const unsigned short* __restrict__ xb,
               const unsigned short* __restrict__ qpb,
               const unsigned short* __restrict__ kpb,
               const unsigned short* __restrict__ vpb,
               unsigned short* __restrict__ Qb, unsigned short* __restrict__ Kbf,
               unsigned short* __restrict__ Vtb) {
  __shared__ unsigned short lA[2 * 64 * 64];
  __shared__ unsigned short lB[2 * 128 * 64];
  const int bid = blockIdx.x;
  const unsigned short *A, *B;
  unsigned short* C;
  int N, bx, by;
  float alpha;
  if (bid < 512) {
    A = xb;  B = qpb; C = Qb;  N = 2048; alpha = 0.125f * 1.44269504088896f;
    bx = bid & 15; by = bid >> 4;
  } else if (bid < 640) {
    int b = bid - 512;
    A = xb;  B = kpb; C = Kbf; N = 512;  alpha = 1.0f;
    bx = b & 3; by = b >> 2;
  } else {
    int b = bid - 640;
    A = vpb; B = xb;  C = Vtb; N = 2048; alpha = 1.0f;
    bx = b & 15; by = b >> 4;
  }
  gemm_body<128, true>(A, B, C, N, 2048, alpha, bx, by, lA, lB);
}

// ---------------- causal GQA flash attention ----------------
// R16: 32-q x 32-kv tiles, 128-thread blocks (2 waves x 16 q-rows), grid
// (32 heads, 64 q-tiles) = 2048 blocks; LDS 18432 B -> EXACTLY 8 blocks/CU,
// 16 waves/CU (4/SIMD = R13's TLP) but 2x the independent chains and 2-wave
// barriers. Per-(q,k) LDS traffic identical to the proven R13 structure; all
// swizzle patterns are structural twins of R13's measured-zero-conflict ones:
//   lK [32][64]   : same 8-chunk rows, key row&7
//   lV interleaved: d-row PAIRS packed into 128B rows (chunk = (d&1)*4+kchunk,
//                   key physrow&7) -> keeps the proven 8-chunk XOR spread
//   P  [16][64]   : wave halves in chunk space (4w+..., exact R13 algebra),
//                   still wave-private -> lgkmcnt-only sync preserved
__global__ __launch_bounds__(128, 4)
void attn32(const unsigned short* __restrict__ Q,
            const unsigned short* __restrict__ Kb,
            const unsigned short* __restrict__ Vt,
            unsigned short* __restrict__ ctx) {
  constexpr int T = 2048, DQ = 2048, DKV = 512, DH = 64;
  const int h    = blockIdx.x;
  const int hkv  = h >> 2;
  const int ya   = blockIdx.y >> 4;
  const int yb   = blockIdx.y & 15;
  const int qi   = (ya == 0) ? yb : (ya == 1) ? 31 - yb : (ya == 2) ? 32 + yb : 63 - yb;
  const int tid  = threadIdx.x;   // 0..127
  const int lane = tid & 63;
  const int w    = tid >> 6;      // 0..1
  const int lr   = lane & 15;
  const int lq   = lane >> 4;     // 0..3
  const int lk   = lq * 8;
  const int sw   = lr & 7;

  __shared__ unsigned short lK[2][32 * 64];   // [k-row][dim]
  __shared__ unsigned short lV[2][32 * 64];   // interleaved: phys row = d>>1
  __shared__ unsigned short P[16][64];        // [q-row][w*32 + k], swizzled chunks

  // K staging: 32 rows x 8 chunks; 128 thr -> 16 rows per gload, 2 gloads
  const int krow0 = tid >> 3;                 // 0..15 (+16 for g=1; &7 invariant)
  const int klc   = (tid & 7) ^ (krow0 & 7);  // logical chunk at phys (tid&7)
  // V staging: phys [32][64]; logical chunk c: d = 2*row + (c>>2), kchunk = c&3
  const int vlc = (tid & 7) ^ (krow0 & 7);
  const int vdp = vlc >> 2;                   // d parity
  const int vkc = vlc & 3;                    // k chunk

  // ones B-fragment for the row-sum MFMA: out-col 0 (lr==0 lanes) = 1.0
  bf16x8 ones_frag;
#pragma unroll
  for (int i = 0; i < 8; ++i) ones_frag[i] = (lr == 0) ? (__bf16)1.0f : (__bf16)0.0f;

#define STAGE_KV(bufidx, kv0)                                                        \
  {                                                                                  \
    _Pragma("unroll")                                                                \
    for (int g = 0; g < 2; ++g)                                                      \
      gload_lds16(Kb + (size_t)((kv0) + krow0 + 16 * g) * DKV + hkv * DH + klc * 8,  \
                  &lK[bufidx][tid * 8 + g * 1024]);                                  \
    _Pragma("unroll")                                                                \
    for (int g = 0; g < 2; ++g)                                                      \
      gload_lds16(Vt + (size_t)(hkv * DH + 2 * (krow0 + 16 * g) + vdp) * T +         \
                      (kv0) + vkc * 8,                                               \
                  &lV[bufidx][tid * 8 + g * 1024]);                                  \
  }

  const int q0b = qi * 32;
  const int qw  = q0b + w * 16;   // this wave's 16 q-rows

  bf16x8 qf0 = *(const bf16x8*)&Q[(size_t)(qw + lr) * DQ + h * DH + lk];
  bf16x8 qf1 = *(const bf16x8*)&Q[(size_t)(qw + lr) * DQ + h * DH + 32 + lk];

  f32x4 oacc[4] = {};
  f32x4 lacc = {};
  float mr[4];
#pragma unroll
  for (int r = 0; r < 4; ++r) mr[r] = -3.0e38f;

  const int nt = qi + 1;   // 32-k tiles
  STAGE_KV(0, 0);
  __syncthreads();  // drains vmcnt(0): buf0 ready

  for (int t = 0; t < nt; ++t) {
    const int kv0 = t * 32;
    const int cur = t & 1;
    if (t + 1 < nt) STAGE_KV(cur ^ 1, kv0 + 32);  // prefetch rides through compute

    // ---- QK^T from LDS (swizzled reads); logits in log2 domain ----
    f32x4 s[2];
    __builtin_amdgcn_s_setprio(1);
#pragma unroll
    for (int n = 0; n < 2; ++n) {
      const int krow = n * 16 + lr;
      bf16x8 kf0 = *(const bf16x8*)&lK[cur][krow * 64 + ((lq ^ sw) << 3)];
      bf16x8 kf1 = *(const bf16x8*)&lK[cur][krow * 64 + (((4 + lq) ^ sw) << 3)];
      f32x4 acc = {};
      acc = __builtin_amdgcn_mfma_f32_16x16x32_bf16(qf0, kf0, acc, 0, 0, 0);
      acc = __builtin_amdgcn_mfma_f32_16x16x32_bf16(qf1, kf1, acc, 0, 0, 0);
      s[n] = acc;
    }
    __builtin_amdgcn_s_setprio(0);

    // ---- causal mask: only the diagonal tile needs it ----
    if (t == qi) {
      const int qr0 = qw + (lq << 2);
#pragma unroll
      for (int n = 0; n < 2; ++n) {
        int kc = kv0 + n * 16 + lr;
#pragma unroll
        for (int r = 0; r < 4; ++r)
          if (kc > qr0 + r) s[n][r] = -3.0e38f;
      }
    }

    // ---- online softmax with defer-max (THR = 8 log2-units) ----
    float lml[4];
#pragma unroll
    for (int r = 0; r < 4; ++r) lml[r] = fmaxf(s[0][r], s[1][r]);
    const bool defer = __all((lml[0] <= mr[0] + 8.f) & (lml[1] <= mr[1] + 8.f) &
                             (lml[2] <= mr[2] + 8.f) & (lml[3] <= mr[3] + 8.f));
    if (!defer) {
#pragma unroll
      for (int r = 0; r < 4; ++r) {
        float ml = lml[r];
        ml = fmaxf(ml, __shfl_xor(ml, 1));
        ml = fmaxf(ml, __shfl_xor(ml, 2));
        ml = fmaxf(ml, __shfl_xor(ml, 4));
        ml = fmaxf(ml, __shfl_xor(ml, 8));
        float mnew = fmaxf(mr[r], ml);
        float sc   = __builtin_amdgcn_exp2f(mr[r] - mnew);
        mr[r] = mnew;
        lacc[r] *= sc;
        oacc[0][r] *= sc; oacc[1][r] *= sc;
        oacc[2][r] *= sc; oacc[3][r] *= sc;
      }
    }

    // ---- P = exp2(s - mr), trunc bf16 -> LDS (wave-half chunks, swizzled) ----
#pragma unroll
    for (int n = 0; n < 2; ++n)
#pragma unroll
      for (int r = 0; r < 4; ++r) {
        float p = __builtin_amdgcn_exp2f(s[n][r] - mr[r]);
        const int prow  = (lq << 2) + r;
        const int chunk = 4 * w + 2 * n + (lr >> 3);
        P[prow][((chunk ^ (prow & 7)) << 3) + (lr & 7)] =
            (unsigned short)(__float_as_uint(p) >> 16);
      }
    asm volatile("s_waitcnt lgkmcnt(0)" ::: "memory");
    __builtin_amdgcn_sched_barrier(0);  // rule #18: keep PV reads below the waitcnt

    // ---- PV + row-sum (ones-MFMA); V read via interleaved-pair layout ----
    __builtin_amdgcn_s_setprio(1);
    {
      bf16x8 pf = *(const bf16x8*)&P[lr][(((4 * w + lq) ^ sw) << 3)];
      lacc = __builtin_amdgcn_mfma_f32_16x16x32_bf16(pf, ones_frag, lacc, 0, 0, 0);
#pragma unroll
      for (int n = 0; n < 4; ++n) {
        // logical d = 16n+lr -> phys row = 8n + (lr>>1); chunk = (lr&1)*4 + lq
        const int vrow = 8 * n + (lr >> 1);
        const int vch  = (((lr & 1) * 4 + lq) ^ (vrow & 7)) << 3;
        bf16x8 vf = *(const bf16x8*)&lV[cur][vrow * 64 + vch];
        oacc[n] = __builtin_amdgcn_mfma_f32_16x16x32_bf16(pf, vf, oacc[n], 0, 0, 0);
      }
    }
    __builtin_amdgcn_s_setprio(0);

    // one barrier per tile: prefetch landed + both waves done with buf[cur]
    __syncthreads();
  }

  float inv[4];
#pragma unroll
  for (int r = 0; r < 4; ++r) {
    float l = __shfl(lacc[r], lane & 48);  // col 0 of own row-group (lr==0 lane)
    inv[r] = 1.f / l;
  }
#pragma unroll
  for (int n = 0; n < 4; ++n)
#pragma unroll
    for (int r = 0; r < 4; ++r) {
      int qrow = qw + (lq << 2) + r;
      ctx[(size_t)qrow * DQ + h * DH + n * 16 + lr] = f2bf(oacc[n][r] * inv[r]);
    }
#undef STAGE_KV
}

extern "C" void kernel_launch(void* const* d_in, const int* in_sizes, int n_in,
                              void* d_out, int out_size, void* d_ws, size_t ws_size,
                              hipStream_t stream) {
  const float* x  = (const float*)d_in[0];
  const float* qp = (const float*)d_in[1];
  const float* kp = (const float*)d_in[2];
  const float* vp = (const float*)d_in[3];
  const float* op = (const float*)d_in[4];

  char* ws = (char*)d_ws;
  const size_t MB = 1024 * 1024;
  unsigned short* xb   = (unsigned short*)(ws + 0 * MB);   // [2048][2048]
  unsigned short* qpb  = (unsigned short*)(ws + 8 * MB);   // [2048][2048]
  unsigned short* kpb  = (unsigned short*)(ws + 16 * MB);  // [512][2048]
  unsigned short* vpb  = (unsigned short*)(ws + 18 * MB);  // [512][2048]
  unsigned short* opT  = (unsigned short*)(ws + 20 * MB);  // [2048][2048] = o_proj^T
  unsigned short* Qb   = (unsigned short*)(ws + 28 * MB);  // [2048][2048]
  unsigned short* Kbf  = (unsigned short*)(ws + 36 * MB);  // [2048][512]
  unsigned short* Vtb  = (unsigned short*)(ws + 38 * MB);  // [512][2048]
  unsigned short* ctxb = (unsigned short*)(ws + 40 * MB);  // [2048][2048]

  // fp32 -> bf16 (4 elementwise inputs + o_proj transpose), ONE dispatch
  cvt_fused<<<11264, 256, 0, stream>>>(x, qp, kp, vp, op, xb, qpb, kpb, vpb, opT);

  // Fused Q+K+V projections (Q scaled by log2(e)/8 -> log2-domain logits)
  gemm_proj<<<768, 256, 0, stream>>>(xb, qpb, kpb, vpb, Qb, Kbf, Vtb);

  // causal GQA attention: 2048 blocks, 8/CU; x = head (XCD-pinned K/V)
  attn32<<<dim3(32, 64), 128, 0, stream>>>(Qb, Kbf, Vtb, ctxb);

  // out = ctx @ o_proj  (via opT, NT form), fp32 epilogue to d_out
  gemm_nt<128, false><<<dim3(16, 32), 256, 0, stream>>>(ctxb, opT, d_out, 2048, 2048, 1.0f);
}

// Round 17
// 112.703 us; speedup vs baseline: 1.1077x; 1.1077x over previous
//
#include <hip/hip_runtime.h>
#include <stdint.h>

typedef __attribute__((ext_vector_type(8))) __bf16 bf16x8;
typedef __attribute__((ext_vector_type(4))) float f32x4;
typedef __attribute__((ext_vector_type(4))) unsigned short u16x4;

typedef __attribute__((address_space(1))) unsigned int as1_uint;
typedef __attribute__((address_space(3))) unsigned int as3_uint;

__device__ __forceinline__ unsigned short f2bf(float f) {
  unsigned int u = __float_as_uint(f);
  u += 0x7fffu + ((u >> 16) & 1u);
  return (unsigned short)(u >> 16);
}

__device__ __forceinline__ void gload_lds16(const void* g, void* l) {
  __builtin_amdgcn_global_load_lds((as1_uint*)(uintptr_t)g, (as3_uint*)(uintptr_t)l,
                                   16, 0, 0);
}

// ---- fused fp32->bf16 converts: 4 elementwise inputs + o_proj transpose ----
// blocks [0,10240): elementwise (x, qp, kp, vp); [10240,11264): transpose op->opT
__global__ __launch_bounds__(256)
void cvt_fused(const float* __restrict__ x, const float* __restrict__ qp,
               const float* __restrict__ kp, const float* __restrict__ vp,
               const float* __restrict__ op,
               unsigned short* __restrict__ xb, unsigned short* __restrict__ qpb,
               unsigned short* __restrict__ kpb, unsigned short* __restrict__ vpb,
               unsigned short* __restrict__ opT) {
  __shared__ unsigned short t[64][72];
  const int b = blockIdx.x;
  if (b < 10240) {
    const float* in;
    unsigned short* out;
    int base;
    if (b < 4096)      { in = x;  out = xb;  base = b; }
    else if (b < 8192) { in = qp; out = qpb; base = b - 4096; }
    else if (b < 9216) { in = kp; out = kpb; base = b - 8192; }
    else               { in = vp; out = vpb; base = b - 9216; }
    const int i = base * 256 + threadIdx.x;
    float4 v = ((const float4*)in)[i];
    u16x4 o;
    o[0] = f2bf(v.x); o[1] = f2bf(v.y); o[2] = f2bf(v.z); o[3] = f2bf(v.w);
    ((u16x4*)out)[i] = o;
    return;
  }
  // transpose-convert: op [2048][2048] -> opT [2048][2048]
  const int tb = b - 10240;
  const int tj = (tb & 31) * 64;
  const int ti = (tb >> 5) * 64;
  const int r  = threadIdx.x >> 4;
  const int c4 = (threadIdx.x & 15) * 4;
#pragma unroll
  for (int i = 0; i < 4; ++i) {
    int row = r + i * 16;
    float4 v = *(const float4*)&op[(size_t)(ti + row) * 2048 + tj + c4];
    t[row][c4]     = f2bf(v.x);
    t[row][c4 + 1] = f2bf(v.y);
    t[row][c4 + 2] = f2bf(v.z);
    t[row][c4 + 3] = f2bf(v.w);
  }
  __syncthreads();
#pragma unroll
  for (int i = 0; i < 4; ++i) {
    int orow = r + i * 16;
    u16x4 o;
    o[0] = t[c4][orow]; o[1] = t[c4 + 1][orow];
    o[2] = t[c4 + 2][orow]; o[3] = t[c4 + 3][orow];
    *(u16x4*)&opT[(size_t)(tj + orow) * 2048 + ti + c4] = o;
  }
}

// ---------------- NT GEMM body: C[M][N] = A[M][K] * B[N][K]^T, bf16 MFMA --------
template <int BN, bool OUT_BF16>
__device__ __forceinline__
void gemm_body(const unsigned short* __restrict__ A,
               const unsigned short* __restrict__ B,
               void* __restrict__ Cout, int N, int K, float alpha,
               int bx, int by, unsigned short* lA, unsigned short* lB) {
  constexpr int NF  = BN / 32;   // 16-col fragments per wave
  constexpr int ASZ = 64 * 64;
  constexpr int BSZ = BN * 64;
  const int tid  = threadIdx.x;
  const int lane = tid & 63;
  const int w    = tid >> 6;
  const int wr   = (w >> 1) * 32;
  const int wc   = (w & 1) * (BN / 2);
  const long brow = (long)by * 64;
  const long bcol = (long)bx * BN;
  const int lr = lane & 15;
  const int lq = lane >> 4;

  const int row0 = tid >> 3;
  const int lc0  = (tid & 7) ^ (row0 & 7);

  f32x4 acc[2][NF] = {};

  const unsigned short* gA = A + (brow + row0) * (long)K + lc0 * 8;
  const unsigned short* gB = B + (bcol + row0) * (long)K + lc0 * 8;

#define G_STAGE(buf, k0)                                                          \
  {                                                                               \
    gload_lds16(gA + (k0),           lA + (buf) * ASZ + tid * 8);                 \
    gload_lds16(gA + 32l * K + (k0), lA + (buf) * ASZ + 2048 + tid * 8);          \
    _Pragma("unroll")                                                             \
    for (int g = 0; g < NF; ++g)                                                  \
      gload_lds16(gB + g * 32l * K + (k0), lB + (buf) * BSZ + g * 2048 + tid * 8);\
  }

  G_STAGE(0, 0);
  __syncthreads();

  for (int k0 = 0; k0 < K; k0 += 64) {
    const int cur = (k0 >> 6) & 1;
    if (k0 + 64 < K) G_STAGE(cur ^ 1, k0 + 64);  // prefetch rides through compute
#pragma unroll
    for (int kk = 0; kk < 2; ++kk) {
      const int j = kk * 4 + lq;
      const int ra0 = wr + lr, ra1 = wr + 16 + lr;
      bf16x8 a0 = *(const bf16x8*)&lA[cur * ASZ + ra0 * 64 + ((j ^ (ra0 & 7)) << 3)];
      bf16x8 a1 = *(const bf16x8*)&lA[cur * ASZ + ra1 * 64 + ((j ^ (ra1 & 7)) << 3)];
      bf16x8 b[NF];
#pragma unroll
      for (int n = 0; n < NF; ++n) {
        const int rb = wc + n * 16 + lr;
        b[n] = *(const bf16x8*)&lB[cur * BSZ + rb * 64 + ((j ^ (rb & 7)) << 3)];
      }
#pragma unroll
      for (int n = 0; n < NF; ++n) {
        acc[0][n] = __builtin_amdgcn_mfma_f32_16x16x32_bf16(a0, b[n], acc[0][n], 0, 0, 0);
        acc[1][n] = __builtin_amdgcn_mfma_f32_16x16x32_bf16(a1, b[n], acc[1][n], 0, 0, 0);
      }
    }
    __syncthreads();
  }
#undef G_STAGE

  const int orow = (int)brow + wr + lq * 4;
  const int ocol = (int)bcol + wc + lr;
#pragma unroll
  for (int m = 0; m < 2; ++m)
#pragma unroll
    for (int n = 0; n < NF; ++n)
#pragma unroll
      for (int r = 0; r < 4; ++r) {
        size_t row = (size_t)(orow + m * 16 + r);
        size_t col = (size_t)(ocol + n * 16);
        float v = acc[m][n][r] * alpha;
        if (OUT_BF16)
          ((unsigned short*)Cout)[row * N + col] = f2bf(v);
        else
          ((float*)Cout)[row * N + col] = v;
      }
}

// o-proj GEMM with T1 XCD-swizzle: grid (16,32) = 512 blocks = 8 x 64.
// swz chunks give each XCD a contiguous run of original ids (shared A-panels).
template <int BN, bool OUT_BF16>
__global__ __launch_bounds__(256)
void gemm_nt(const unsigned short* __restrict__ A,
             const unsigned short* __restrict__ B,
             void* __restrict__ Cout, int N, int K, float alpha) {
  __shared__ unsigned short lA[2 * 64 * 64];
  __shared__ unsigned short lB[2 * BN * 64];
  const int flat  = (int)blockIdx.x + (int)gridDim.x * (int)blockIdx.y;
  const int total = (int)(gridDim.x * gridDim.y);
  const int cpx   = total >> 3;              // total is a multiple of 8
  const int swz   = (flat & 7) * cpx + (flat >> 3);
  const int bx    = swz % (int)gridDim.x;
  const int by    = swz / (int)gridDim.x;
  gemm_body<BN, OUT_BF16>(A, B, Cout, N, K, alpha, bx, by, lA, lB);
}

// Fused Q+K+V projections, one dispatch, 768 blocks (= 8 x 96), T1 XCD-swizzle
// then flat decode (all BN=128):
//   [0,512)   Q = xb @ qpb^T (alpha=log2e/8), 16x * 32y
//   [512,640) K = xb @ kpb^T,                  4x * 32y
//   [640,768) Vt = vpb @ xb^T,                16x *  8y
__global__ __launch_bounds__(256)
void gemm_proj(const unsigned short* __restrict__ xb,
               const unsigned short* __restrict__ qpb,
               const unsigned short* __restrict__ kpb,
               const unsigned short* __restrict__ vpb,
               unsigned short* __restrict__ Qb, unsigned short* __restrict__ Kbf,
               unsigned short* __restrict__ Vtb) {
  __shared__ unsigned short lA[2 * 64 * 64];
  __shared__ unsigned short lB[2 * 128 * 64];
  const int raw = blockIdx.x;
  const int bid = (raw & 7) * 96 + (raw >> 3);   // bijective on [0,768)
  const unsigned short *A, *B;
  unsigned short* C;
  int N, bx, by;
  float alpha;
  if (bid < 512) {
    A = xb;  B = qpb; C = Qb;  N = 2048; alpha = 0.125f * 1.44269504088896f;
    bx = bid & 15; by = bid >> 4;
  } else if (bid < 640) {
    int b = bid - 512;
    A = xb;  B = kpb; C = Kbf; N = 512;  alpha = 1.0f;
    bx = b & 3; by = b >> 2;
  } else {
    int b = bid - 640;
    A = vpb; B = xb;  C = Vtb; N = 2048; alpha = 1.0f;
    bx = b & 15; by = b >> 4;
  }
  gemm_body<128, true>(A, B, C, N, 2048, alpha, bx, by, lA, lB);
}

// ---------------- causal GQA flash attention ----------------
// R17 = R15/R13-exact proven body (47.2 us, conflicts 0, 4 blocks/CU x 4 waves,
// LDS-pipe-saturated local optimum; R14 2-wave and R16 32-kv variants both
// regressed). Grid (32 heads, 32 q-tiles); x = head -> XCD-pinned K/V;
// qi bijection {b,15-b,16+b,31-b}[y>>3] balances the 4 co-resident blocks/CU.
__global__ __launch_bounds__(256, 4)
void attn64(const unsigned short* __restrict__ Q,
            const unsigned short* __restrict__ Kb,
            const unsigned short* __restrict__ Vt,
            unsigned short* __restrict__ ctx) {
  constexpr int T = 2048, DQ = 2048, DKV = 512, DH = 64;
  const int h    = blockIdx.x;
  const int hkv  = h >> 2;
  const int ya   = blockIdx.y >> 3;
  const int yb   = blockIdx.y & 7;
  const int qi   = (ya == 0) ? yb : (ya == 1) ? 15 - yb : (ya == 2) ? 16 + yb : 31 - yb;
  const int tid  = threadIdx.x;
  const int lane = tid & 63;
  const int w    = tid >> 6;
  const int lr   = lane & 15;
  const int lq   = lane >> 4;   // 0..3
  const int lk   = lq * 8;
  const int sw   = lr & 7;      // row-derived swizzle key for fragment reads

  __shared__ unsigned short lK[2][64 * 64];
  __shared__ unsigned short lV[2][64 * 64];
  __shared__ unsigned short P[4][16][64];   // unpadded; XOR-swizzled chunks

  const int row0 = tid >> 3;
  const int lc0  = (tid & 7) ^ (row0 & 7);

  // ones B-fragment for the row-sum MFMA: out-col 0 (lr==0 lanes) = 1.0 over all k
  bf16x8 ones_frag;
#pragma unroll
  for (int i = 0; i < 8; ++i) ones_frag[i] = (lr == 0) ? (__bf16)1.0f : (__bf16)0.0f;

#define STAGE_KV(bufidx, kv0)                                                        \
  {                                                                                  \
    gload_lds16(Kb + (size_t)((kv0) + row0) * DKV + hkv * DH + lc0 * 8,              \
                &lK[bufidx][tid * 8]);                                               \
    gload_lds16(Kb + (size_t)((kv0) + row0 + 32) * DKV + hkv * DH + lc0 * 8,         \
                &lK[bufidx][2048 + tid * 8]);                                        \
    gload_lds16(Vt + (size_t)(hkv * DH + row0) * T + (kv0) + lc0 * 8,                \
                &lV[bufidx][tid * 8]);                                               \
    gload_lds16(Vt + (size_t)(hkv * DH + row0 + 32) * T + (kv0) + lc0 * 8,           \
                &lV[bufidx][2048 + tid * 8]);                                        \
  }

  const int q0b = qi * 64;
  const int qw  = q0b + w * 16;

  bf16x8 qf0 = *(const bf16x8*)&Q[(size_t)(qw + lr) * DQ + h * DH + lk];
  bf16x8 qf1 = *(const bf16x8*)&Q[(size_t)(qw + lr) * DQ + h * DH + 32 + lk];

  f32x4 oacc[4] = {};
  f32x4 lacc = {};
  float mr[4];
#pragma unroll
  for (int r = 0; r < 4; ++r) mr[r] = -3.0e38f;

  const int nt = qi + 1;
  STAGE_KV(0, 0);
  __syncthreads();  // drains vmcnt(0): buf0 ready

  for (int t = 0; t < nt; ++t) {
    const int kv0 = t * 64;
    const int cur = t & 1;
    if (t + 1 < nt) STAGE_KV(cur ^ 1, kv0 + 64);  // prefetch rides through compute

    // ---- QK^T from LDS (swizzled reads); logits in log2 domain ----
    f32x4 s[4];
    __builtin_amdgcn_s_setprio(1);
#pragma unroll
    for (int n = 0; n < 4; ++n) {
      const int krow = n * 16 + lr;
      bf16x8 kf0 = *(const bf16x8*)&lK[cur][krow * 64 + ((lq ^ sw) << 3)];
      bf16x8 kf1 = *(const bf16x8*)&lK[cur][krow * 64 + (((4 + lq) ^ sw) << 3)];
      f32x4 acc = {};
      acc = __builtin_amdgcn_mfma_f32_16x16x32_bf16(qf0, kf0, acc, 0, 0, 0);
      acc = __builtin_amdgcn_mfma_f32_16x16x32_bf16(qf1, kf1, acc, 0, 0, 0);
      s[n] = acc;
    }
    __builtin_amdgcn_s_setprio(0);

    // ---- causal mask: only the diagonal tile needs it ----
    if (t == qi) {
      const int qr0 = qw + (lq << 2);
#pragma unroll
      for (int n = 0; n < 4; ++n) {
        int kc = kv0 + n * 16 + lr;
#pragma unroll
        for (int r = 0; r < 4; ++r)
          if (kc > qr0 + r) s[n][r] = -3.0e38f;
      }
    }

    // ---- online softmax with defer-max (THR = 8 log2-units) ----
    float lml[4];
#pragma unroll
    for (int r = 0; r < 4; ++r)
      lml[r] = fmaxf(fmaxf(s[0][r], s[1][r]), fmaxf(s[2][r], s[3][r]));
    const bool defer = __all((lml[0] <= mr[0] + 8.f) & (lml[1] <= mr[1] + 8.f) &
                             (lml[2] <= mr[2] + 8.f) & (lml[3] <= mr[3] + 8.f));
    if (!defer) {
#pragma unroll
      for (int r = 0; r < 4; ++r) {
        float ml = lml[r];
        ml = fmaxf(ml, __shfl_xor(ml, 1));
        ml = fmaxf(ml, __shfl_xor(ml, 2));
        ml = fmaxf(ml, __shfl_xor(ml, 4));
        ml = fmaxf(ml, __shfl_xor(ml, 8));
        float mnew = fmaxf(mr[r], ml);
        float sc   = __builtin_amdgcn_exp2f(mr[r] - mnew);
        mr[r] = mnew;
        lacc[r] *= sc;
        oacc[0][r] *= sc; oacc[1][r] *= sc;
        oacc[2][r] *= sc; oacc[3][r] *= sc;
      }
    }

    // ---- P = exp2(s - mr) (bounded by 2^8 under defer) ----
#pragma unroll
    for (int n = 0; n < 4; ++n)
#pragma unroll
      for (int r = 0; r < 4; ++r)
        s[n][r] = __builtin_amdgcn_exp2f(s[n][r] - mr[r]);

    // ---- P (C-layout) -> LDS, truncating bf16, XOR-swizzled chunks ----
    // write (row = 4lq+r, col = 16n+lr): chunk (2n + lr>>3) ^ (row&7), elem lr&7
#pragma unroll
    for (int n = 0; n < 4; ++n)
#pragma unroll
      for (int r = 0; r < 4; ++r) {
        const int prow = (lq << 2) + r;
        P[w][prow][(((2 * n + (lr >> 3)) ^ (prow & 7)) << 3) + (lr & 7)] =
            (unsigned short)(__float_as_uint(s[n][r]) >> 16);
      }
    asm volatile("s_waitcnt lgkmcnt(0)" ::: "memory");
    __builtin_amdgcn_sched_barrier(0);  // rule #18: keep PV reads below the waitcnt

    // ---- PV + row-sum (ones-MFMA) from LDS (swizzled P & V reads) ----
    __builtin_amdgcn_s_setprio(1);
#pragma unroll
    for (int ks = 0; ks < 2; ++ks) {
      bf16x8 pf = *(const bf16x8*)&P[w][lr][((ks * 4 + lq) ^ sw) << 3];
      lacc = __builtin_amdgcn_mfma_f32_16x16x32_bf16(pf, ones_frag, lacc, 0, 0, 0);
#pragma unroll
      for (int n = 0; n < 4; ++n) {
        const int vrow = n * 16 + lr;
        bf16x8 vf = *(const bf16x8*)&lV[cur][vrow * 64 + (((ks * 4 + lq) ^ sw) << 3)];
        oacc[n] = __builtin_amdgcn_mfma_f32_16x16x32_bf16(pf, vf, oacc[n], 0, 0, 0);
      }
    }
    __builtin_amdgcn_s_setprio(0);

    // one barrier per tile: prefetch landed + all waves done with buf[cur]
    __syncthreads();
  }

  float inv[4];
#pragma unroll
  for (int r = 0; r < 4; ++r) {
    float l = __shfl(lacc[r], lane & 48);  // col 0 of own row-group (lr==0 lane)
    inv[r] = 1.f / l;
  }
#pragma unroll
  for (int n = 0; n < 4; ++n)
#pragma unroll
    for (int r = 0; r < 4; ++r) {
      int qrow = qw + (lq << 2) + r;
      ctx[(size_t)qrow * DQ + h * DH + n * 16 + lr] = f2bf(oacc[n][r] * inv[r]);
    }
#undef STAGE_KV
}

extern "C" void kernel_launch(void* const* d_in, const int* in_sizes, int n_in,
                              void* d_out, int out_size, void* d_ws, size_t ws_size,
                              hipStream_t stream) {
  const float* x  = (const float*)d_in[0];
  const float* qp = (const float*)d_in[1];
  const float* kp = (const float*)d_in[2];
  const float* vp = (const float*)d_in[3];
  const float* op = (const float*)d_in[4];

  char* ws = (char*)d_ws;
  const size_t MB = 1024 * 1024;
  unsigned short* xb   = (unsigned short*)(ws + 0 * MB);   // [2048][2048]
  unsigned short* qpb  = (unsigned short*)(ws + 8 * MB);   // [2048][2048]
  unsigned short* kpb  = (unsigned short*)(ws + 16 * MB);  // [512][2048]
  unsigned short* vpb  = (unsigned short*)(ws + 18 * MB);  // [512][2048]
  unsigned short* opT  = (unsigned short*)(ws + 20 * MB);  // [2048][2048] = o_proj^T
  unsigned short* Qb   = (unsigned short*)(ws + 28 * MB);  // [2048][2048]
  unsigned short* Kbf  = (unsigned short*)(ws + 36 * MB);  // [2048][512]
  unsigned short* Vtb  = (unsigned short*)(ws + 38 * MB);  // [512][2048]
  unsigned short* ctxb = (unsigned short*)(ws + 40 * MB);  // [2048][2048]

  // fp32 -> bf16 (4 elementwise inputs + o_proj transpose), ONE dispatch
  cvt_fused<<<11264, 256, 0, stream>>>(x, qp, kp, vp, op, xb, qpb, kpb, vpb, opT);

  // Fused Q+K+V projections (Q scaled by log2(e)/8), XCD-swizzled
  gemm_proj<<<768, 256, 0, stream>>>(xb, qpb, kpb, vpb, Qb, Kbf, Vtb);

  // causal GQA attention: x = head (XCD-pinned K/V), y -> balanced qi bijection
  attn64<<<dim3(32, 32), 256, 0, stream>>>(Qb, Kbf, Vtb, ctxb);

  // out = ctx @ o_proj  (via opT, NT form), fp32 epilogue, XCD-swizzled
  gemm_nt<128, false><<<dim3(16, 32), 256, 0, stream>>>(ctxb, opT, d_out, 2048, 2048, 1.0f);
}

// Round 18
// 110.971 us; speedup vs baseline: 1.1250x; 1.0156x over previous
//
#include <hip/hip_runtime.h>
#include <stdint.h>

typedef __attribute__((ext_vector_type(8))) __bf16 bf16x8;
typedef __attribute__((ext_vector_type(8))) unsigned short u16x8;
typedef __attribute__((ext_vector_type(4))) float f32x4;
typedef __attribute__((ext_vector_type(4))) unsigned short u16x4;

typedef __attribute__((address_space(1))) unsigned int as1_uint;
typedef __attribute__((address_space(3))) unsigned int as3_uint;

__device__ __forceinline__ unsigned short f2bf(float f) {
  unsigned int u = __float_as_uint(f);
  u += 0x7fffu + ((u >> 16) & 1u);
  return (unsigned short)(u >> 16);
}

__device__ __forceinline__ void gload_lds16(const void* g, void* l) {
  __builtin_amdgcn_global_load_lds((as1_uint*)(uintptr_t)g, (as3_uint*)(uintptr_t)l,
                                   16, 0, 0);
}

// ---- fused fp32->bf16 converts: 4 elementwise inputs + o_proj transpose ----
// blocks [0,10240): elementwise (x, qp, kp, vp); [10240,11264): transpose op->opT
__global__ __launch_bounds__(256)
void cvt_fused(const float* __restrict__ x, const float* __restrict__ qp,
               const float* __restrict__ kp, const float* __restrict__ vp,
               const float* __restrict__ op,
               unsigned short* __restrict__ xb, unsigned short* __restrict__ qpb,
               unsigned short* __restrict__ kpb, unsigned short* __restrict__ vpb,
               unsigned short* __restrict__ opT) {
  __shared__ unsigned short t[64][72];
  const int b = blockIdx.x;
  if (b < 10240) {
    const float* in;
    unsigned short* out;
    int base;
    if (b < 4096)      { in = x;  out = xb;  base = b; }
    else if (b < 8192) { in = qp; out = qpb; base = b - 4096; }
    else if (b < 9216) { in = kp; out = kpb; base = b - 8192; }
    else               { in = vp; out = vpb; base = b - 9216; }
    const int i = base * 256 + threadIdx.x;
    float4 v = ((const float4*)in)[i];
    u16x4 o;
    o[0] = f2bf(v.x); o[1] = f2bf(v.y); o[2] = f2bf(v.z); o[3] = f2bf(v.w);
    ((u16x4*)out)[i] = o;
    return;
  }
  // transpose-convert: op [2048][2048] -> opT [2048][2048]
  const int tb = b - 10240;
  const int tj = (tb & 31) * 64;
  const int ti = (tb >> 5) * 64;
  const int r  = threadIdx.x >> 4;
  const int c4 = (threadIdx.x & 15) * 4;
#pragma unroll
  for (int i = 0; i < 4; ++i) {
    int row = r + i * 16;
    float4 v = *(const float4*)&op[(size_t)(ti + row) * 2048 + tj + c4];
    t[row][c4]     = f2bf(v.x);
    t[row][c4 + 1] = f2bf(v.y);
    t[row][c4 + 2] = f2bf(v.z);
    t[row][c4 + 3] = f2bf(v.w);
  }
  __syncthreads();
#pragma unroll
  for (int i = 0; i < 4; ++i) {
    int orow = r + i * 16;
    u16x4 o;
    o[0] = t[c4][orow]; o[1] = t[c4 + 1][orow];
    o[2] = t[c4 + 2][orow]; o[3] = t[c4 + 3][orow];
    *(u16x4*)&opT[(size_t)(tj + orow) * 2048 + ti + c4] = o;
  }
}

// ---------------- NT GEMM body: C[M][N] = A[M][K] * B[N][K]^T, bf16 MFMA --------
template <int BN, bool OUT_BF16>
__device__ __forceinline__
void gemm_body(const unsigned short* __restrict__ A,
               const unsigned short* __restrict__ B,
               void* __restrict__ Cout, int N, int K, float alpha,
               int bx, int by, unsigned short* lA, unsigned short* lB) {
  constexpr int NF  = BN / 32;   // 16-col fragments per wave
  constexpr int ASZ = 64 * 64;
  constexpr int BSZ = BN * 64;
  const int tid  = threadIdx.x;
  const int lane = tid & 63;
  const int w    = tid >> 6;
  const int wr   = (w >> 1) * 32;
  const int wc   = (w & 1) * (BN / 2);
  const long brow = (long)by * 64;
  const long bcol = (long)bx * BN;
  const int lr = lane & 15;
  const int lq = lane >> 4;

  const int row0 = tid >> 3;
  const int lc0  = (tid & 7) ^ (row0 & 7);

  f32x4 acc[2][NF] = {};

  const unsigned short* gA = A + (brow + row0) * (long)K + lc0 * 8;
  const unsigned short* gB = B + (bcol + row0) * (long)K + lc0 * 8;

#define G_STAGE(buf, k0)                                                          \
  {                                                                               \
    gload_lds16(gA + (k0),           lA + (buf) * ASZ + tid * 8);                 \
    gload_lds16(gA + 32l * K + (k0), lA + (buf) * ASZ + 2048 + tid * 8);          \
    _Pragma("unroll")                                                             \
    for (int g = 0; g < NF; ++g)                                                  \
      gload_lds16(gB + g * 32l * K + (k0), lB + (buf) * BSZ + g * 2048 + tid * 8);\
  }

  G_STAGE(0, 0);
  __syncthreads();

  for (int k0 = 0; k0 < K; k0 += 64) {
    const int cur = (k0 >> 6) & 1;
    if (k0 + 64 < K) G_STAGE(cur ^ 1, k0 + 64);  // prefetch rides through compute
#pragma unroll
    for (int kk = 0; kk < 2; ++kk) {
      const int j = kk * 4 + lq;
      const int ra0 = wr + lr, ra1 = wr + 16 + lr;
      bf16x8 a0 = *(const bf16x8*)&lA[cur * ASZ + ra0 * 64 + ((j ^ (ra0 & 7)) << 3)];
      bf16x8 a1 = *(const bf16x8*)&lA[cur * ASZ + ra1 * 64 + ((j ^ (ra1 & 7)) << 3)];
      bf16x8 b[NF];
#pragma unroll
      for (int n = 0; n < NF; ++n) {
        const int rb = wc + n * 16 + lr;
        b[n] = *(const bf16x8*)&lB[cur * BSZ + rb * 64 + ((j ^ (rb & 7)) << 3)];
      }
#pragma unroll
      for (int n = 0; n < NF; ++n) {
        acc[0][n] = __builtin_amdgcn_mfma_f32_16x16x32_bf16(a0, b[n], acc[0][n], 0, 0, 0);
        acc[1][n] = __builtin_amdgcn_mfma_f32_16x16x32_bf16(a1, b[n], acc[1][n], 0, 0, 0);
      }
    }
    __syncthreads();
  }
#undef G_STAGE

  const int orow = (int)brow + wr + lq * 4;
  const int ocol = (int)bcol + wc + lr;
#pragma unroll
  for (int m = 0; m < 2; ++m)
#pragma unroll
    for (int n = 0; n < NF; ++n)
#pragma unroll
      for (int r = 0; r < 4; ++r) {
        size_t row = (size_t)(orow + m * 16 + r);
        size_t col = (size_t)(ocol + n * 16);
        float v = acc[m][n][r] * alpha;
        if (OUT_BF16)
          ((unsigned short*)Cout)[row * N + col] = f2bf(v);
        else
          ((float*)Cout)[row * N + col] = v;
      }
}

// o-proj GEMM with T1 XCD-swizzle: grid (16,32) = 512 blocks = 8 x 64.
template <int BN, bool OUT_BF16>
__global__ __launch_bounds__(256)
void gemm_nt(const unsigned short* __restrict__ A,
             const unsigned short* __restrict__ B,
             void* __restrict__ Cout, int N, int K, float alpha) {
  __shared__ unsigned short lA[2 * 64 * 64];
  __shared__ unsigned short lB[2 * BN * 64];
  const int flat  = (int)blockIdx.x + (int)gridDim.x * (int)blockIdx.y;
  const int total = (int)(gridDim.x * gridDim.y);
  const int cpx   = total >> 3;              // total is a multiple of 8
  const int swz   = (flat & 7) * cpx + (flat >> 3);
  const int bx    = swz % (int)gridDim.x;
  const int by    = swz / (int)gridDim.x;
  gemm_body<BN, OUT_BF16>(A, B, Cout, N, K, alpha, bx, by, lA, lB);
}

// Fused Q+K+V projections, one dispatch, 768 blocks (= 8 x 96), T1 XCD-swizzle
//   [0,512)   Q = xb @ qpb^T (alpha=log2e/8), 16x * 32y
//   [512,640) K = xb @ kpb^T,                  4x * 32y
//   [640,768) Vt = vpb @ xb^T,                16x *  8y
__global__ __launch_bounds__(256)
void gemm_proj(const unsigned short* __restrict__ xb,
               const unsigned short* __restrict__ qpb,
               const unsigned short* __restrict__ kpb,
               const unsigned short* __restrict__ vpb,
               unsigned short* __restrict__ Qb, unsigned short* __restrict__ Kbf,
               unsigned short* __restrict__ Vtb) {
  __shared__ unsigned short lA[2 * 64 * 64];
  __shared__ unsigned short lB[2 * 128 * 64];
  const int raw = blockIdx.x;
  const int bid = (raw & 7) * 96 + (raw >> 3);   // bijective on [0,768)
  const unsigned short *A, *B;
  unsigned short* C;
  int N, bx, by;
  float alpha;
  if (bid < 512) {
    A = xb;  B = qpb; C = Qb;  N = 2048; alpha = 0.125f * 1.44269504088896f;
    bx = bid & 15; by = bid >> 4;
  } else if (bid < 640) {
    int b = bid - 512;
    A = xb;  B = kpb; C = Kbf; N = 512;  alpha = 1.0f;
    bx = b & 3; by = b >> 2;
  } else {
    int b = bid - 640;
    A = vpb; B = xb;  C = Vtb; N = 2048; alpha = 1.0f;
    bx = b & 15; by = b >> 4;
  }
  gemm_body<128, true>(A, B, C, N, 2048, alpha, bx, by, lA, lB);
}

// ---------------- causal GQA flash attention ----------------
// R18: ZERO-SHUFFLE IN-REGISTER P. Swapped QK^T (s = mfma(K,Q): identical LDS
// reads/Q-frags, C-layout gives lane (lr,lq) scores for q=lr at k-POSITION
// 16n+4lq+r) + permuted K staging (source row sigma^-1(p) = 32*(p>>5) +
// 8*((p>>2)&3) + 4*((p>>4)&1) + (p&3)) so position-row == global
// k = 32(n>>1)+8lq+4(n&1)+r. The lane's 16 exp'd scores then pack DIRECTLY
// into PV's two A-fragments (k = 32ks+8lq+j) -- no P LDS array, no lgkmcnt,
// no cross-lane moves. Row state (mr,l) is one scalar/lane (q=lr); row reduce
// = 2 shfl_xor; rescale broadcast 4 shfl on !defer only; l sums the
// truncation-reconstructed p (preserves num/denom cancellation).
// Everything else (staging sync, V layout/reads, oacc layout, grid, qi
// bijection, XCD pinning) identical to the proven R17 body. LDS 32768 B.
__global__ __launch_bounds__(256, 4)
void attn64(const unsigned short* __restrict__ Q,
            const unsigned short* __restrict__ Kb,
            const unsigned short* __restrict__ Vt,
            unsigned short* __restrict__ ctx) {
  constexpr int T = 2048, DQ = 2048, DKV = 512, DH = 64;
  const int h    = blockIdx.x;
  const int hkv  = h >> 2;
  const int ya   = blockIdx.y >> 3;
  const int yb   = blockIdx.y & 7;
  const int qi   = (ya == 0) ? yb : (ya == 1) ? 15 - yb : (ya == 2) ? 16 + yb : 31 - yb;
  const int tid  = threadIdx.x;
  const int lane = tid & 63;
  const int lr   = lane & 15;
  const int lq   = lane >> 4;   // 0..3
  const int lk   = lq * 8;
  const int sw   = lr & 7;      // row-derived swizzle key for fragment reads

  __shared__ unsigned short lK[2][64 * 64];
  __shared__ unsigned short lV[2][64 * 64];

  const int row0 = tid >> 3;                 // LDS position row 0..31 (+32)
  const int lc0  = (tid & 7) ^ (row0 & 7);   // XOR involution chunk
  // sigma^-1 for K: global k row stored at position row0 (+32 for g=1)
  const int kperm = 8 * ((row0 >> 2) & 3) + 4 * ((row0 >> 4) & 1) + (row0 & 3);

#define STAGE_KV(bufidx, kv0)                                                        \
  {                                                                                  \
    gload_lds16(Kb + (size_t)((kv0) + kperm) * DKV + hkv * DH + lc0 * 8,             \
                &lK[bufidx][tid * 8]);                                               \
    gload_lds16(Kb + (size_t)((kv0) + kperm + 32) * DKV + hkv * DH + lc0 * 8,        \
                &lK[bufidx][2048 + tid * 8]);                                        \
    gload_lds16(Vt + (size_t)(hkv * DH + row0) * T + (kv0) + lc0 * 8,                \
                &lV[bufidx][tid * 8]);                                               \
    gload_lds16(Vt + (size_t)(hkv * DH + row0 + 32) * T + (kv0) + lc0 * 8,           \
                &lV[bufidx][2048 + tid * 8]);                                        \
  }

  const int q0b = qi * 64;
  const int qw  = q0b + (tid >> 6) * 16;   // wave w owns q-rows qw..qw+15

  bf16x8 qf0 = *(const bf16x8*)&Q[(size_t)(qw + lr) * DQ + h * DH + lk];
  bf16x8 qf1 = *(const bf16x8*)&Q[(size_t)(qw + lr) * DQ + h * DH + 32 + lk];

  f32x4 oacc[4] = {};
  float l  = 0.f;
  float mr = -3.0e38f;

  const int nt = qi + 1;
  STAGE_KV(0, 0);
  __syncthreads();  // drains vmcnt(0): buf0 ready

  for (int t = 0; t < nt; ++t) {
    const int kv0 = t * 64;
    const int cur = t & 1;
    if (t + 1 < nt) STAGE_KV(cur ^ 1, kv0 + 64);  // prefetch rides through compute

    // ---- swapped QK^T: s[n] = K-tile(n) x Q; identical LDS reads to R17 ----
    f32x4 s[4];
    __builtin_amdgcn_s_setprio(1);
#pragma unroll
    for (int n = 0; n < 4; ++n) {
      const int krow = n * 16 + lr;   // LDS position row
      bf16x8 kf0 = *(const bf16x8*)&lK[cur][krow * 64 + ((lq ^ sw) << 3)];
      bf16x8 kf1 = *(const bf16x8*)&lK[cur][krow * 64 + (((4 + lq) ^ sw) << 3)];
      f32x4 acc = {};
      acc = __builtin_amdgcn_mfma_f32_16x16x32_bf16(kf0, qf0, acc, 0, 0, 0);
      acc = __builtin_amdgcn_mfma_f32_16x16x32_bf16(kf1, qf1, acc, 0, 0, 0);
      s[n] = acc;
    }
    __builtin_amdgcn_s_setprio(0);
    // lane (lr,lq) now holds S[k_global = kv0+32(n>>1)+8lq+4(n&1)+r][q = qw+lr]

    // ---- causal mask: only the diagonal tile needs it ----
    if (t == qi) {
      const int kb = kv0 + 8 * lq;
      const int qg = qw + lr;
#pragma unroll
      for (int n = 0; n < 4; ++n) {
        const int kn = kb + 32 * (n >> 1) + 4 * (n & 1);
#pragma unroll
        for (int r = 0; r < 4; ++r)
          if (kn + r > qg) s[n][r] = -3.0e38f;
      }
    }

    // ---- online softmax with defer-max (THR = 8 log2-units); q=lr per lane ----
    float lml = fmaxf(fmaxf(fmaxf(s[0][0], s[0][1]), fmaxf(s[0][2], s[0][3])),
                      fmaxf(fmaxf(s[1][0], s[1][1]), fmaxf(s[1][2], s[1][3])));
    lml = fmaxf(lml, fmaxf(fmaxf(s[2][0], s[2][1]), fmaxf(s[2][2], s[2][3])));
    lml = fmaxf(lml, fmaxf(fmaxf(s[3][0], s[3][1]), fmaxf(s[3][2], s[3][3])));
    const bool defer = __all(lml <= mr + 8.f);
    if (!defer) {
      float rm = lml;
      rm = fmaxf(rm, __shfl_xor(rm, 16));
      rm = fmaxf(rm, __shfl_xor(rm, 32));
      float mnew = fmaxf(mr, rm);
      float sc   = __builtin_amdgcn_exp2f(mr - mnew);
      mr = mnew;
      l *= sc;
      float sc4[4];
#pragma unroll
      for (int r = 0; r < 4; ++r) sc4[r] = __shfl(sc, (lq << 2) + r);
#pragma unroll
      for (int m = 0; m < 4; ++m)
#pragma unroll
        for (int r = 0; r < 4; ++r) oacc[m][r] *= sc4[r];
    }

    // ---- P = exp2(s - mr): trunc-pack straight into PV A-fragments ----
    u16x8 pk0, pk1;
    float ps = 0.f;
#pragma unroll
    for (int n = 0; n < 4; ++n)
#pragma unroll
      for (int r = 0; r < 4; ++r) {
        float p = __builtin_amdgcn_exp2f(s[n][r] - mr);
        unsigned int u = __float_as_uint(p);
        ps += __uint_as_float(u & 0xFFFF0000u);   // sum exactly what PV consumes
        const int j = ((n & 1) << 2) + r;         // k offset within 8-slice
        if (n < 2) pk0[j] = (unsigned short)(u >> 16);
        else       pk1[j] = (unsigned short)(u >> 16);
      }
    ps += __shfl_xor(ps, 16);
    ps += __shfl_xor(ps, 32);
    l += ps;
    bf16x8 pf0 = *(bf16x8*)&pk0;   // k = 8lq..8lq+7
    bf16x8 pf1 = *(bf16x8*)&pk1;   // k = 32+8lq..+7

    // ---- PV from registers + LDS V (swizzled reads, unchanged) ----
    __builtin_amdgcn_s_setprio(1);
#pragma unroll
    for (int ks = 0; ks < 2; ++ks) {
      bf16x8 pf = ks ? pf1 : pf0;
#pragma unroll
      for (int m = 0; m < 4; ++m) {
        const int vrow = m * 16 + lr;
        bf16x8 vf = *(const bf16x8*)&lV[cur][vrow * 64 + (((ks * 4 + lq) ^ sw) << 3)];
        oacc[m] = __builtin_amdgcn_mfma_f32_16x16x32_bf16(pf, vf, oacc[m], 0, 0, 0);
      }
    }
    __builtin_amdgcn_s_setprio(0);

    // one barrier per tile: prefetch landed + all waves done with buf[cur]
    __syncthreads();
  }

  float inv[4];
#pragma unroll
  for (int r = 0; r < 4; ++r)
    inv[r] = 1.f / __shfl(l, (lq << 2) + r);   // l lives at lane lr == q-row
#pragma unroll
  for (int m = 0; m < 4; ++m)
#pragma unroll
    for (int r = 0; r < 4; ++r) {
      int qrow = qw + (lq << 2) + r;
      ctx[(size_t)qrow * DQ + h * DH + m * 16 + lr] = f2bf(oacc[m][r] * inv[r]);
    }
#undef STAGE_KV
}

extern "C" void kernel_launch(void* const* d_in, const int* in_sizes, int n_in,
                              void* d_out, int out_size, void* d_ws, size_t ws_size,
                              hipStream_t stream) {
  const float* x  = (const float*)d_in[0];
  const float* qp = (const float*)d_in[1];
  const float* kp = (const float*)d_in[2];
  const float* vp = (const float*)d_in[3];
  const float* op = (const float*)d_in[4];

  char* ws = (char*)d_ws;
  const size_t MB = 1024 * 1024;
  unsigned short* xb   = (unsigned short*)(ws + 0 * MB);   // [2048][2048]
  unsigned short* qpb  = (unsigned short*)(ws + 8 * MB);   // [2048][2048]
  unsigned short* kpb  = (unsigned short*)(ws + 16 * MB);  // [512][2048]
  unsigned short* vpb  = (unsigned short*)(ws + 18 * MB);  // [512][2048]
  unsigned short* opT  = (unsigned short*)(ws + 20 * MB);  // [2048][2048] = o_proj^T
  unsigned short* Qb   = (unsigned short*)(ws + 28 * MB);  // [2048][2048]
  unsigned short* Kbf  = (unsigned short*)(ws + 36 * MB);  // [2048][512]
  unsigned short* Vtb  = (unsigned short*)(ws + 38 * MB);  // [512][2048]
  unsigned short* ctxb = (unsigned short*)(ws + 40 * MB);  // [2048][2048]

  // fp32 -> bf16 (4 elementwise inputs + o_proj transpose), ONE dispatch
  cvt_fused<<<11264, 256, 0, stream>>>(x, qp, kp, vp, op, xb, qpb, kpb, vpb, opT);

  // Fused Q+K+V projections (Q scaled by log2(e)/8), XCD-swizzled
  gemm_proj<<<768, 256, 0, stream>>>(xb, qpb, kpb, vpb, Qb, Kbf, Vtb);

  // causal GQA attention: x = head (XCD-pinned K/V), y -> balanced qi bijection
  attn64<<<dim3(32, 32), 256, 0, stream>>>(Qb, Kbf, Vtb, ctxb);

  // out = ctx @ o_proj  (via opT, NT form), fp32 epilogue, XCD-swizzled
  gemm_nt<128, false><<<dim3(16, 32), 256, 0, stream>>>(ctxb, opT, d_out, 2048, 2048, 1.0f);
}